// Round 10
// baseline (441.329 us; speedup 1.0000x reference)
//
#include <hip/hip_runtime.h>
#include <hip/hip_fp16.h>
#include <math.h>

#define FEAT 128
#define HID  64
#define PSPLIT 16              // pool splits per group

typedef _Float16 f16_t;
typedef f16_t half8 __attribute__((ext_vector_type(8)));
typedef float  f32x4 __attribute__((ext_vector_type(4)));

// ---------------- CSR build: global-atomic degree -> scan -> atomic scatter ----
// (replaces the 2-level LDS-histogram bucket sort: that ran at 1 block/CU with
//  contended LDS atomics = latency-serial ~110us; global atomics over 100K
//  distinct addresses with 2048-block TLP hide completely)

__global__ void deg_k(const int* __restrict__ dst, int* __restrict__ deg, int e) {
    int i = blockIdx.x * 256 + threadIdx.x;
    int stride = gridDim.x * 256;
    for (; i < e; i += stride)
        atomicAdd(&deg[dst[i]], 1);
}

__global__ void scan1_k(int* __restrict__ data, int* __restrict__ aux, int L) {
    __shared__ int s[1024];
    int gid = blockIdx.x * 1024 + threadIdx.x;
    int v = (gid < L) ? data[gid] : 0;
    s[threadIdx.x] = v;
    __syncthreads();
    for (int off = 1; off < 1024; off <<= 1) {
        int t = (threadIdx.x >= off) ? s[threadIdx.x - off] : 0;
        __syncthreads();
        s[threadIdx.x] += t;
        __syncthreads();
    }
    if (gid < L) data[gid] = s[threadIdx.x] - v;            // exclusive in block
    if (threadIdx.x == 1023) aux[blockIdx.x] = s[1023];     // block total
}

__global__ void scan2_k(int* aux, int naux) {
    __shared__ int s[1024];
    int v = (threadIdx.x < naux) ? aux[threadIdx.x] : 0;
    s[threadIdx.x] = v;
    __syncthreads();
    for (int off = 1; off < 1024; off <<= 1) {
        int t = (threadIdx.x >= off) ? s[threadIdx.x - off] : 0;
        __syncthreads();
        s[threadIdx.x] += t;
        __syncthreads();
    }
    if (threadIdx.x < naux) aux[threadIdx.x] = s[threadIdx.x] - v;
}

__global__ void fin_k(const int* __restrict__ sc, const int* __restrict__ aux,
                      int* __restrict__ rowptr, int* __restrict__ cur,
                      float* __restrict__ dinv, int n, int e) {
    int i = blockIdx.x * 256 + threadIdx.x;
    if (i >= n) return;
    int rp = sc[i] + aux[i >> 10];
    rowptr[i] = rp;
    cur[i] = rp;
    int next = (i + 1 < n) ? (sc[i + 1] + aux[(i + 1) >> 10]) : e;
    dinv[i] = 1.0f / sqrtf(1.0f + (float)(next - rp));
    if (i == n - 1) rowptr[n] = e;
}

__global__ void scat_k(const int* __restrict__ src, const int* __restrict__ dst,
                       int* __restrict__ cur, int* __restrict__ col, int e) {
    int i = blockIdx.x * 256 + threadIdx.x;
    int stride = gridDim.x * 256;
    for (; i < e; i += stride) {
        int p = atomicAdd(&cur[dst[i]], 1);
        col[p] = src[i];
    }
}

// ---------------- dense transform: out[n,64] = fp16((X[n,128] @ W1) * dinv[row]) ----

__global__ __launch_bounds__(256, 3)
void gemm_tile_k(const float* __restrict__ X, const float* __restrict__ W,
                 const float* __restrict__ dinv, __half* __restrict__ out, int n) {
    constexpr int K = FEAT;
    __shared__ float sX[64][K + 4];
    __shared__ float sW[64][64];       // one 64-row slab of W
    const int row0 = blockIdx.x * 64;
    const int t  = threadIdx.x;
    const int tx = t & 15;
    const int ty = t >> 4;

    const float* xb = X + (size_t)row0 * K;
#pragma unroll
    for (int it = 0; it < K / 16; ++it) {
        int fl = it * 1024 + t * 4;
        int r  = fl >> 7;
        int k  = fl & (K - 1);
        float4 v = make_float4(0.f, 0.f, 0.f, 0.f);
        if (row0 + r < n) v = *(const float4*)(xb + fl);
        *(float4*)&sX[r][k] = v;
    }

    float acc[4][4] = {};
#pragma unroll
    for (int ph = 0; ph < K / 64; ++ph) {
        __syncthreads();
#pragma unroll
        for (int it = 0; it < 4; ++it) {
            int fl = it * 1024 + t * 4;
            *(float4*)&sW[fl >> 6][fl & 63] = *(const float4*)(W + ph * 64 * HID + fl);
        }
        __syncthreads();

#pragma unroll 8
        for (int k = 0; k < 64; k += 4) {
            float4 a[4], b[4];
#pragma unroll
            for (int i = 0; i < 4; i++) a[i] = *(float4*)&sX[ty * 4 + i][ph * 64 + k];
#pragma unroll
            for (int j = 0; j < 4; j++) b[j] = *(float4*)&sW[k + j][tx * 4];
#pragma unroll
            for (int i = 0; i < 4; i++) {
                acc[i][0] = fmaf(a[i].x, b[0].x, acc[i][0]);
                acc[i][1] = fmaf(a[i].x, b[0].y, acc[i][1]);
                acc[i][2] = fmaf(a[i].x, b[0].z, acc[i][2]);
                acc[i][3] = fmaf(a[i].x, b[0].w, acc[i][3]);
                acc[i][0] = fmaf(a[i].y, b[1].x, acc[i][0]);
                acc[i][1] = fmaf(a[i].y, b[1].y, acc[i][1]);
                acc[i][2] = fmaf(a[i].y, b[1].z, acc[i][2]);
                acc[i][3] = fmaf(a[i].y, b[1].w, acc[i][3]);
                acc[i][0] = fmaf(a[i].z, b[2].x, acc[i][0]);
                acc[i][1] = fmaf(a[i].z, b[2].y, acc[i][1]);
                acc[i][2] = fmaf(a[i].z, b[2].z, acc[i][2]);
                acc[i][3] = fmaf(a[i].z, b[2].w, acc[i][3]);
                acc[i][0] = fmaf(a[i].w, b[3].x, acc[i][0]);
                acc[i][1] = fmaf(a[i].w, b[3].y, acc[i][1]);
                acc[i][2] = fmaf(a[i].w, b[3].z, acc[i][2]);
                acc[i][3] = fmaf(a[i].w, b[3].w, acc[i][3]);
            }
        }
    }

#pragma unroll
    for (int i = 0; i < 4; i++) {
        int gr = row0 + ty * 4 + i;
        if (gr < n) {
            float sc = dinv[gr];
            union { __half2 h[2]; unsigned long long u; } pk;
            pk.h[0] = __floats2half2_rn(acc[i][0] * sc, acc[i][1] * sc);
            pk.h[1] = __floats2half2_rn(acc[i][2] * sc, acc[i][3] * sc);
            *(unsigned long long*)(out + (size_t)gr * HID + tx * 4) = pk.u;
        }
    }
}

// ---------------- layer-1 gather (plain; fp16 h output) ----------------

__global__ void gather1_k(const __half* __restrict__ tS, const int* __restrict__ rowptr,
                          const int* __restrict__ col, const float* __restrict__ dinv,
                          const float* __restrict__ b, __half* __restrict__ out, int n) {
    int node = (int)((blockIdx.x * (size_t)blockDim.x + threadIdx.x) >> 5);
    int lane = threadIdx.x & 31;
    if (node >= n) return;
    int beg = rowptr[node], end = rowptr[node + 1];
    const __half2* tl = (const __half2*)tS + lane;   // row stride = 32 half2
    float2 acc = __half22float2(tl[node * 32]);      // self-loop term
    int e = beg;
    for (; e + 16 <= end; e += 16) {
        int s[16];
        __half2 v[16];
#pragma unroll
        for (int j = 0; j < 16; j++) s[j] = col[e + j];
#pragma unroll
        for (int j = 0; j < 16; j++) v[j] = tl[s[j] * 32];
        float2 t0 = make_float2(0.f, 0.f), t1 = make_float2(0.f, 0.f);
#pragma unroll
        for (int j = 0; j < 8; j++) {
            float2 f = __half22float2(v[j]);
            t0.x += f.x; t0.y += f.y;
        }
#pragma unroll
        for (int j = 8; j < 16; j++) {
            float2 f = __half22float2(v[j]);
            t1.x += f.x; t1.y += f.y;
        }
        acc.x += t0.x + t1.x;
        acc.y += t0.y + t1.y;
    }
    for (; e + 4 <= end; e += 4) {
        __half2 v0 = tl[col[e] * 32];
        __half2 v1 = tl[col[e + 1] * 32];
        __half2 v2 = tl[col[e + 2] * 32];
        __half2 v3 = tl[col[e + 3] * 32];
        float2 f0 = __half22float2(v0), f1 = __half22float2(v1);
        float2 f2 = __half22float2(v2), f3 = __half22float2(v3);
        acc.x += (f0.x + f1.x) + (f2.x + f3.x);
        acc.y += (f0.y + f1.y) + (f2.y + f3.y);
    }
    for (; e < end; ++e) {
        float2 f = __half22float2(tl[col[e] * 32]);
        acc.x += f.x; acc.y += f.y;
    }
    float d = dinv[node];
    float2 bb = *(const float2*)(b + 2 * lane);
    float h0 = fmaxf(fmaf(d, acc.x, bb.x), 0.0f);
    float h1 = fmaxf(fmaf(d, acc.y, bb.y), 0.0f);
    ((__half2*)out)[node * 32 + lane] = __floats2half2_rn(h0, h1);
}

// ---------------- t2: tS2[n,64] = fp16((h16 @ W2) * dinv) via MFMA 16x16x32 f16 ----

__global__ __launch_bounds__(256)
void t2_k(const __half* __restrict__ h, const float* __restrict__ W2,
          const float* __restrict__ dinv, __half* __restrict__ out, int n) {
    const int wave  = threadIdx.x >> 6;
    const int l     = threadIdx.x & 63;
    const int strip = blockIdx.x * 4 + wave;
    const int r0    = strip * 16;
    if (r0 >= n) return;
    const int col = l & 15;
    const int kb  = l >> 4;          // 0..3

    // B-frags: bf[t][kk][j] = W2[kk*32 + kb*8 + j][t*16 + col]  (fp32 -> fp16)
    half8 bf[4][2];
#pragma unroll
    for (int t = 0; t < 4; ++t)
#pragma unroll
        for (int kk = 0; kk < 2; ++kk)
#pragma unroll
            for (int j = 0; j < 8; ++j)
                bf[t][kk][j] = (f16_t)W2[(kk * 32 + kb * 8 + j) * HID + t * 16 + col];

    // A-frags: contiguous 16B loads of the h row
    const int arow = r0 + col;       // row = lane&15
    const __half* ap = h + (size_t)arow * HID + kb * 8;
    half8 a0 = *(const half8*)(ap);
    half8 a1 = *(const half8*)(ap + 32);

    f32x4 acc[4] = {};
#pragma unroll
    for (int t = 0; t < 4; ++t) {
        acc[t] = __builtin_amdgcn_mfma_f32_16x16x32_f16(a0, bf[t][0], acc[t], 0, 0, 0);
        acc[t] = __builtin_amdgcn_mfma_f32_16x16x32_f16(a1, bf[t][1], acc[t], 0, 0, 0);
    }

    // epilogue: lane holds cols {col+16t}, rows r0 + kb*4 + r
    const int rbase = r0 + kb * 4;
#pragma unroll
    for (int r = 0; r < 4; ++r) {
        int gr = rbase + r;
        if (gr < n) {
            float dv = dinv[gr];
#pragma unroll
            for (int t = 0; t < 4; ++t)
                out[(size_t)gr * HID + t * 16 + col] = __float2half(acc[t][r] * dv);
        }
    }
}

// ---------------- layer-2 gather (logits fused; h written fp16 for pool) ----

__global__ void gather2_k(const __half* __restrict__ tS, const int* __restrict__ rowptr,
                          const int* __restrict__ col, const float* __restrict__ dinv,
                          const float* __restrict__ b, __half* __restrict__ out,
                          const float* __restrict__ Wa, const float* __restrict__ ba,
                          float* __restrict__ logits, int n) {
    int node = (int)((blockIdx.x * (size_t)blockDim.x + threadIdx.x) >> 5);
    int lane = threadIdx.x & 31;
    if (node >= n) return;
    int beg = rowptr[node], end = rowptr[node + 1];
    const __half2* tl = (const __half2*)tS + lane;
    float2 acc = __half22float2(tl[node * 32]);
    int e = beg;
    for (; e + 16 <= end; e += 16) {
        int s[16];
        __half2 v[16];
#pragma unroll
        for (int j = 0; j < 16; j++) s[j] = col[e + j];
#pragma unroll
        for (int j = 0; j < 16; j++) v[j] = tl[s[j] * 32];
        float2 t0 = make_float2(0.f, 0.f), t1 = make_float2(0.f, 0.f);
#pragma unroll
        for (int j = 0; j < 8; j++) {
            float2 f = __half22float2(v[j]);
            t0.x += f.x; t0.y += f.y;
        }
#pragma unroll
        for (int j = 8; j < 16; j++) {
            float2 f = __half22float2(v[j]);
            t1.x += f.x; t1.y += f.y;
        }
        acc.x += t0.x + t1.x;
        acc.y += t0.y + t1.y;
    }
    for (; e + 4 <= end; e += 4) {
        __half2 v0 = tl[col[e] * 32];
        __half2 v1 = tl[col[e + 1] * 32];
        __half2 v2 = tl[col[e + 2] * 32];
        __half2 v3 = tl[col[e + 3] * 32];
        float2 f0 = __half22float2(v0), f1 = __half22float2(v1);
        float2 f2 = __half22float2(v2), f3 = __half22float2(v3);
        acc.x += (f0.x + f1.x) + (f2.x + f3.x);
        acc.y += (f0.y + f1.y) + (f2.y + f3.y);
    }
    for (; e < end; ++e) {
        float2 f = __half22float2(tl[col[e] * 32]);
        acc.x += f.x; acc.y += f.y;
    }
    float d = dinv[node];
    float2 bb = *(const float2*)(b + 2 * lane);
    float h0 = fmaxf(fmaf(d, acc.x, bb.x), 0.0f);
    float h1 = fmaxf(fmaf(d, acc.y, bb.y), 0.0f);
    ((__half2*)out)[node * 32 + lane] = __floats2half2_rn(h0, h1);
    float2 wa = *(const float2*)(Wa + 2 * lane);
    float p = h0 * wa.x + h1 * wa.y;
#pragma unroll
    for (int off = 16; off > 0; off >>= 1) p += __shfl_down(p, off, 32);
    if (lane == 0) logits[node] = p + ba[0];
}

// ---------------- parallel mean-pool: 64 groups x 16 splits, branch-free ----

__global__ void pool2_k(const __half* __restrict__ h, const int* __restrict__ batch,
                        float* __restrict__ pooled, int n) {
    const int gid  = blockIdx.x / PSPLIT;
    const int part = blockIdx.x % PSPLIT;
    int lo = 0, hi = n;
    while (lo < hi) { int m = (lo + hi) >> 1; if (batch[m] < gid) lo = m + 1; else hi = m; }
    const int b0 = lo;
    hi = n;
    while (lo < hi) { int m = (lo + hi) >> 1; if (batch[m] < gid + 1) lo = m + 1; else hi = m; }
    const int b1 = lo;
    const int chunk = (b1 - b0 + PSPLIT - 1) / PSPLIT;
    const int r0 = b0 + part * chunk;
    const int r1 = min(r0 + chunk, b1);
    const int lane = threadIdx.x & 31;
    const int rg   = threadIdx.x >> 5;       // 8 rows in flight
    const __half2* hp = (const __half2*)h + lane;
    float2 acc = make_float2(0.f, 0.f);
    for (int i = r0 + rg; i < r1; i += 8) {
        float2 f = __half22float2(hp[(size_t)i * 32]);
        acc.x += f.x; acc.y += f.y;
    }
    __shared__ float2 red[8][32];
    red[rg][lane] = acc;
    __syncthreads();
    if (threadIdx.x < 32) {
        float2 s = make_float2(0.f, 0.f);
#pragma unroll
        for (int r = 0; r < 8; r++) { s.x += red[r][threadIdx.x].x; s.y += red[r][threadIdx.x].y; }
        atomicAdd(&pooled[gid * HID + 2 * threadIdx.x], s.x);
        atomicAdd(&pooled[gid * HID + 2 * threadIdx.x + 1], s.y);
    }
}

// ---------------- value head (counts via binary search on sorted batch) ----------------

__global__ void value_k(const float* __restrict__ pooled, const int* __restrict__ batch,
                        const float* __restrict__ Wc, const float* __restrict__ bc,
                        float* __restrict__ val, int n, int g) {
    int gw   = (int)((blockIdx.x * (size_t)blockDim.x + threadIdx.x) >> 6);
    int lane = threadIdx.x & 63;
    if (gw >= g) return;
    int lo = 0, hi = n;
    while (lo < hi) { int m = (lo + hi) >> 1; if (batch[m] < gw) lo = m + 1; else hi = m; }
    int b0 = lo;
    lo = 0; hi = n;
    while (lo < hi) { int m = (lo + hi) >> 1; if (batch[m] < gw + 1) lo = m + 1; else hi = m; }
    float cnt = fmaxf((float)(lo - b0), 1.0f);
    float p = (pooled[gw * HID + lane] / cnt) * Wc[lane];
#pragma unroll
    for (int off = 32; off > 0; off >>= 1) p += __shfl_down(p, off);
    if (lane == 0) val[gw] = p + bc[0];
}

extern "C" void kernel_launch(void* const* d_in, const int* in_sizes, int n_in,
                              void* d_out, int out_size, void* d_ws, size_t ws_size,
                              hipStream_t stream) {
    const float* x     = (const float*)d_in[0];
    const int*   ei    = (const int*)d_in[1];
    const int*   batch = (const int*)d_in[2];
    const float* W1    = (const float*)d_in[3];
    const float* b1    = (const float*)d_in[4];
    const float* W2    = (const float*)d_in[5];
    const float* b2    = (const float*)d_in[6];
    const float* Wa    = (const float*)d_in[7];
    const float* ba    = (const float*)d_in[8];
    const float* Wc    = (const float*)d_in[9];
    const float* bc    = (const float*)d_in[10];

    const int n = in_sizes[0] / FEAT;   // 100000
    const int e = in_sizes[1] / 2;      // 1600000
    const int g = out_size - n;         // 64
    const int* src = ei;
    const int* dst = ei + e;

    // workspace layout
    float*    ws     = (float*)d_ws;
    float*    dinv   = ws;                               // n
    float*    bufA   = dinv + n;                         // n*HID floats (tS1 / tS2 fp16)
    float*    bufB   = bufA + (size_t)n * HID;           // n*HID floats (h16 / h2 fp16)
    float*    pooled = bufB + (size_t)n * HID;           // g*HID
    int*      deg    = (int*)(pooled + (size_t)g * HID); // n (degree -> exclusive scan)
    int*      aux    = deg + n;                          // 1024
    int*      rowptr = aux + 1024;                       // n+1
    int*      cur    = rowptr + n + 1;                   // n (scatter cursors)
    int*      col    = cur + n;                          // e
    __half*   tS1    = (__half*)bufA;                    // layer-1 transformed
    __half*   h16    = (__half*)bufB;                    // layer-1 h (gather1 out)
    __half*   tS2    = (__half*)bufA;                    // layer-2 transformed (t2 out)
    __half*   h2     = (__half*)bufB;                    // layer-2 h (gather2 out)

    const int B = 256;
    const int gridT  = (n + 63) / 64;
    const int gridG  = (int)(((size_t)n * 32 + B - 1) / B);  // 32-lane group per node
    const int strips = (n + 15) / 16;
    const int gridT2 = (strips + 3) / 4;                      // 4 waves/block, 1 strip/wave
    const int nb1    = (n + 1023) / 1024;                     // scan blocks over n degrees

    (void)hipMemsetAsync(pooled, 0, (size_t)g * HID * sizeof(float), stream);
    (void)hipMemsetAsync(deg, 0, (size_t)n * sizeof(int), stream);

    // CSR build: degree histogram (global atomics, full TLP) -> scan -> scatter
    deg_k<<<1024, B, 0, stream>>>(dst, deg, e);
    scan1_k<<<nb1, 1024, 0, stream>>>(deg, aux, n);
    scan2_k<<<1, 1024, 0, stream>>>(aux, nb1);
    fin_k<<<(n + B - 1) / B, B, 0, stream>>>(deg, aux, rowptr, cur, dinv, n, e);
    scat_k<<<2048, B, 0, stream>>>(src, dst, cur, col, e);

    // layer 1: dense transform + gather
    gemm_tile_k<<<gridT, B, 0, stream>>>(x, W1, dinv, tS1, n);
    gather1_k<<<gridG, B, 0, stream>>>(tS1, rowptr, col, dinv, b1, h16, n);

    // layer-2 transform via MFMA, then gather (logits fused)
    t2_k<<<gridT2, B, 0, stream>>>(h16, W2, dinv, tS2, n);
    gather2_k<<<gridG, B, 0, stream>>>(tS2, rowptr, col, dinv, b2, h2,
                                       Wa, ba, (float*)d_out, n);

    // heads
    pool2_k<<<g * PSPLIT, B, 0, stream>>>(h2, batch, pooled, n);
    value_k<<<(g * 64 + B - 1) / B, B, 0, stream>>>(pooled, batch, Wc, bc,
                                                    (float*)d_out + n, n, g);
}